// Round 9
// baseline (184.777 us; speedup 1.0000x reference)
//
#include <hip/hip_runtime.h>
#include <math.h>
#include <stdint.h>
#include <stddef.h>

// ProbSparse multi-head attention (Informer-style), fp32, MI355X.
// Heads share q,k,v; only the threefry-sampled key set differs per head.
// S (the shared 2x1024x1024 score matrix) lives in d_out and is consumed
// (k_M, k_pv) before k_fill/k_corr overwrite d_out with the result.
// Softmax uses no max-shift: |S|/32 <= ~1.5 for N(0,1) inputs -> exp safe.

#define BB     2
#define LQ     1024
#define LK     1024
#define DH     64
#define NH     16
#define DM     1024
#define USEL   34
#define USAMP  7097
#define NSLICE 8   // j-dimension slices in k_means
#define NJ     8   // j-dimension slices in k_pv
#define JS     (LK / NJ)   // 128

#define THREEFRY_PARTITIONABLE 1

// ---------------- threefry2x32 (matches jax._src.prng) ----------------
__device__ __forceinline__ uint32_t rotl32(uint32_t x, int d) {
  return (x << d) | (x >> (32 - d));
}

__device__ __forceinline__ void threefry2x32(uint32_t k0, uint32_t k1,
                                             uint32_t x0, uint32_t x1,
                                             uint32_t& o0, uint32_t& o1) {
  uint32_t ks2 = k0 ^ k1 ^ 0x1BD11BDAu;
  x0 += k0; x1 += k1;
#define TFR(r) { x0 += x1; x1 = rotl32(x1, (r)); x1 ^= x0; }
  TFR(13) TFR(15) TFR(26) TFR(6)
  x0 += k1; x1 += ks2 + 1u;
  TFR(17) TFR(29) TFR(16) TFR(24)
  x0 += ks2; x1 += k0 + 2u;
  TFR(13) TFR(15) TFR(26) TFR(6)
  x0 += k0; x1 += k1 + 3u;
  TFR(17) TFR(29) TFR(16) TFR(24)
  x0 += k1; x1 += ks2 + 4u;
  TFR(13) TFR(15) TFR(26) TFR(6)
  x0 += ks2; x1 += k0 + 5u;
#undef TFR
  o0 = x0; o1 = x1;
}

// ---------------- k0: zero counts/base/kmean/vmean/delta_raw/ssum ----------------
__global__ void k_zero(unsigned* __restrict__ p, int n) {
  int i = blockIdx.x * blockDim.x + threadIdx.x;
  if (i < n) p[i] = 0u;
}

// ---------------- k1: sample key indices, histogram counts ----------------
__global__ void k_sample(unsigned* __restrict__ counts) {
  __shared__ uint32_t sk[2];
  int h = blockIdx.y;
  if (threadIdx.x == 0) {
    uint32_t hk0, hk1, t0, t1;
#if THREEFRY_PARTITIONABLE
    threefry2x32(0u, 42u, 0u, (uint32_t)h, hk0, hk1);   // head_keys = split (foldlike)
    threefry2x32(hk0, hk1, 0u, 1u, t0, t1);             // k2 = split(head_key)[1]
    sk[0] = t0; sk[1] = t1;
#else
    uint32_t a0, a1, b0, b1, c0, c1;
    int i0 = 2 * h, i1 = 2 * h + 1;
    if (i0 < 16) { threefry2x32(0u, 42u, (uint32_t)i0, (uint32_t)(i0 + 16), a0, a1); hk0 = a0; }
    else         { threefry2x32(0u, 42u, (uint32_t)(i0 - 16), (uint32_t)i0, a0, a1); hk0 = a1; }
    if (i1 < 16) { threefry2x32(0u, 42u, (uint32_t)i1, (uint32_t)(i1 + 16), a0, a1); hk1 = a0; }
    else         { threefry2x32(0u, 42u, (uint32_t)(i1 - 16), (uint32_t)i1, a0, a1); hk1 = a1; }
    threefry2x32(hk0, hk1, 0u, 2u, b0, b1);
    threefry2x32(hk0, hk1, 1u, 3u, c0, c1);
    sk[0] = b1; sk[1] = c1;
#endif
  }
  __syncthreads();
  int j = blockIdx.x * blockDim.x + threadIdx.x;
  if (j >= USAMP) return;
  for (int b = 0; b < BB; b++) {
    uint32_t o0, o1, bits;
#if THREEFRY_PARTITIONABLE
    threefry2x32(sk[0], sk[1], 0u, (uint32_t)(b * USAMP + j), o0, o1);
    bits = o0 ^ o1;
#else
    threefry2x32(sk[0], sk[1], (uint32_t)j, (uint32_t)(j + USAMP), o0, o1);
    bits = (b == 0) ? o0 : o1;
#endif
    // randint span=1024 divides 2^16 -> multiplier term = 0 -> idx = bits % 1024
    atomicAdd(&counts[((size_t)h * BB + b) * LK + (bits & (LK - 1))], 1u);
  }
}

// ------- k2: kmean (count-weighted) + vmean — j-sliced, float4, atomic combine
__global__ __launch_bounds__(256) void k_means(const float* __restrict__ kk,
                                               const float* __restrict__ v,
                                               const unsigned* __restrict__ counts,
                                               float* __restrict__ kmean,
                                               float* __restrict__ vmean) {
  int task = blockIdx.y, s = blockIdx.x, t = threadIdx.x;
  int d4 = t & 15, jsub = t >> 4;               // 16 float4-lanes over d, 16 j-rows
  __shared__ float4 part[16][16];               // [jsub][d4]
  float4 acc = make_float4(0.f, 0.f, 0.f, 0.f);
  if (task < NH * BB) {
    int b = task & 1;
    const unsigned* cnt = counts + (size_t)task * LK;
    const float4* kb4 = (const float4*)(kk + (size_t)b * LK * DH);
#pragma unroll
    for (int jj = 0; jj < LK / (16 * NSLICE); jj++) {   // 8 independent loads in flight
      int j = s * (LK / NSLICE) + jsub + 16 * jj;
      float c = (float)cnt[j];
      float4 kv = kb4[j * 16 + d4];
      acc.x += c * kv.x; acc.y += c * kv.y; acc.z += c * kv.z; acc.w += c * kv.w;
    }
  } else {
    int b = task - NH * BB;
    const float4* vb4 = (const float4*)(v + (size_t)b * LK * DH);
#pragma unroll
    for (int jj = 0; jj < LK / (16 * NSLICE); jj++) {
      int j = s * (LK / NSLICE) + jsub + 16 * jj;
      float4 kv = vb4[j * 16 + d4];
      acc.x += kv.x; acc.y += kv.y; acc.z += kv.z; acc.w += kv.w;
    }
  }
  part[jsub][d4] = acc;
  __syncthreads();
  if (t < 16) {
    float4 sum = part[0][t];
#pragma unroll
    for (int x = 1; x < 16; x++) {
      float4 p = part[x][t];
      sum.x += p.x; sum.y += p.y; sum.z += p.z; sum.w += p.w;
    }
    float scale = (task < NH * BB) ? (1.0f / (float)USAMP) : (1.0f / (float)LK);
    float* dst = (task < NH * BB) ? (kmean + (size_t)task * DH)
                                  : (vmean + (size_t)(task - NH * BB) * DH);
    atomicAdd(&dst[t * 4 + 0], sum.x * scale);
    atomicAdd(&dst[t * 4 + 1], sum.y * scale);
    atomicAdd(&dst[t * 4 + 2], sum.z * scale);
    atomicAdd(&dst[t * 4 + 3], sum.w * scale);
  }
}

// ------- k3: S[b,i,j] = q_i . k_j — transposed LDS, outer-product inner loop
__global__ __launch_bounds__(256) void k_scores(const float* __restrict__ q,
                                                const float* __restrict__ k,
                                                float* __restrict__ S) {
  __shared__ float Qt[DH][68];
  __shared__ float Kt[DH][68];
  int b = blockIdx.z;
  int i0 = blockIdx.y * 64, j0 = blockIdx.x * 64;
  int t = threadIdx.x;
  const float* qb = q + ((size_t)b * LQ + i0) * DH;
  const float* kb = k + ((size_t)b * LK + j0) * DH;
#pragma unroll
  for (int rep = 0; rep < 4; rep++) {
    int lin = (rep * 256 + t) * 4;
    int r = lin >> 6, c = lin & 63;
    float4 qv = *(const float4*)(qb + (size_t)r * DH + c);
    float4 kv = *(const float4*)(kb + (size_t)r * DH + c);
    Qt[c][r] = qv.x; Qt[c + 1][r] = qv.y; Qt[c + 2][r] = qv.z; Qt[c + 3][r] = qv.w;
    Kt[c][r] = kv.x; Kt[c + 1][r] = kv.y; Kt[c + 2][r] = kv.z; Kt[c + 3][r] = kv.w;
  }
  __syncthreads();
  int tx = t & 15, ty = t >> 4;
  float acc[4][4] = {};
#pragma unroll 8
  for (int d = 0; d < DH; d++) {
    float4 av = *(const float4*)&Qt[d][ty * 4];
    float4 bv = *(const float4*)&Kt[d][tx * 4];
    acc[0][0] += av.x * bv.x; acc[0][1] += av.x * bv.y; acc[0][2] += av.x * bv.z; acc[0][3] += av.x * bv.w;
    acc[1][0] += av.y * bv.x; acc[1][1] += av.y * bv.y; acc[1][2] += av.y * bv.z; acc[1][3] += av.y * bv.w;
    acc[2][0] += av.z * bv.x; acc[2][1] += av.z * bv.y; acc[2][2] += av.z * bv.z; acc[2][3] += av.z * bv.w;
    acc[3][0] += av.w * bv.x; acc[3][1] += av.w * bv.y; acc[3][2] += av.w * bv.z; acc[3][3] += av.w * bv.w;
  }
  float* Sb = S + ((size_t)b * LQ + i0) * LK + j0;
#pragma unroll
  for (int r = 0; r < 4; r++) {
    *(float4*)(Sb + (size_t)(ty * 4 + r) * LK + tx * 4) =
        make_float4(acc[r][0], acc[r][1], acc[r][2], acc[r][3]);
  }
}

// ------- k4: M[h,b,i] = max_{sampled j} S[i,j] - q_i.kmean[h,b] — all heads, one S pass
__global__ __launch_bounds__(256) void k_M(const float* __restrict__ q,
                                           const float* __restrict__ S,
                                           const unsigned* __restrict__ counts,
                                           const float* __restrict__ kmean,
                                           float* __restrict__ M) {
  int b = blockIdx.y;
  __shared__ uint32_t mask[NH][LK / 32];
  int t = threadIdx.x;
  for (int w = t; w < NH * (LK / 32); w += 256) {
    int h = w >> 5, blk = w & 31;
    const unsigned* cnt = counts + ((size_t)h * BB + b) * LK + blk * 32;
    uint32_t m = 0;
    for (int z = 0; z < 32; z++) m |= (cnt[z] != 0u ? 1u : 0u) << z;
    mask[h][blk] = m;
  }
  __syncthreads();
  int lane = t & 63, w4 = t >> 6;
  int i = blockIdx.x * 4 + w4;
  const float* Srow = S + ((size_t)b * LQ + i) * LK;
  float mx[NH];
#pragma unroll
  for (int h = 0; h < NH; h++) mx[h] = -INFINITY;
  for (int j = lane; j < LK; j += 64) {
    float s = Srow[j];
#pragma unroll
    for (int h = 0; h < NH; h++) {
      bool on = (mask[h][j >> 5] >> (j & 31)) & 1u;
      mx[h] = fmaxf(mx[h], on ? s : -INFINITY);
    }
  }
#pragma unroll
  for (int h = 0; h < NH; h++) {
#pragma unroll
    for (int off = 32; off > 0; off >>= 1) mx[h] = fmaxf(mx[h], __shfl_xor(mx[h], off));
  }
  float qv = q[((size_t)b * LQ + i) * DH + lane];  // lane == d (DH==64)
#pragma unroll
  for (int h = 0; h < NH; h++) {
    float p = qv * kmean[((size_t)h * BB + b) * DH + lane];
#pragma unroll
    for (int off = 32; off > 0; off >>= 1) p += __shfl_xor(p, off);
    mx[h] -= p;
  }
  if (lane == 0) {
#pragma unroll
    for (int h = 0; h < NH; h++) M[((size_t)h * BB + b) * LQ + i] = mx[h];
  }
}

// ---- k5: top-34 per (h,b) — ONE wave, M in registers, zero barriers/LDS ----
__global__ __launch_bounds__(64) void k_topk(const float* __restrict__ M,
                                             int* __restrict__ topidx) {
  int hb = blockIdx.x, lane = threadIdx.x;
  const float* Mh = M + (size_t)hb * LQ;
  float r[16];
#pragma unroll
  for (int c = 0; c < 16; c++) r[c] = Mh[c * 64 + lane];  // coalesced
  for (int u = 0; u < USEL; u++) {
    float bv = -INFINITY; int bi = 0x7fffffff;
#pragma unroll
    for (int c = 0; c < 16; c++) {       // ascending idx + strict '>' => lowest idx on tie
      float x = r[c];
      int i = c * 64 + lane;
      if (x > bv) { bv = x; bi = i; }
    }
#pragma unroll
    for (int off = 32; off > 0; off >>= 1) {
      float ov = __shfl_xor(bv, off);
      int   oi = __shfl_xor(bi, off);
      if (ov > bv || (ov == bv && oi < bi)) { bv = ov; bi = oi; }
    }
    // butterfly leaves identical winner on all 64 lanes
    if (lane == 0) topidx[hb * USEL + u] = bi;
    int wc = bi >> 6, wl = bi & 63;
#pragma unroll
    for (int c = 0; c < 16; c++)         // compile-time index: stays in registers
      if (c == wc && lane == wl) r[c] = -INFINITY;
  }
}

// ------- k6: PV j-sliced — delta_raw[hb,u,:] += sum_{j in slice} exp(S/32) * v[j,:]
// grid (NJ, NH*BB). No max-shift (|S|/32 <= ~1.5). Also accumulates ssum partials.
__global__ __launch_bounds__(256) void k_pv(const float* __restrict__ S,
                                            const float* __restrict__ v,
                                            const int* __restrict__ topidx,
                                            float* __restrict__ delta_raw,
                                            float* __restrict__ ssum) {
  int hb = blockIdx.y, s = blockIdx.x, b = hb & 1;
  int t = threadIdx.x, d = t & 63, g = t >> 6;
  __shared__ float p[USEL][JS];        // 17 KB
  __shared__ float part[4][USEL][DH];  // 34.8 KB
  for (int idx = t; idx < USEL * JS; idx += 256) {
    int u = idx >> 7, jj = idx & (JS - 1);
    int i = topidx[hb * USEL + u];
    float xs = S[((size_t)b * LQ + i) * LK + s * JS + jj];
    p[u][jj] = expf(xs * 0.03125f);    // 1/sqrt(1024) = 1/32 exactly
  }
  __syncthreads();
  // each wave owns 32 contiguous jj; v values held in registers
  float vreg[32];
  const float* vb = v + ((size_t)b * LK + s * JS + g * 32) * DH + d;
#pragma unroll
  for (int jj = 0; jj < 32; jj++) vreg[jj] = vb[(size_t)jj * DH];
  for (int u = 0; u < USEL; u++) {
    float acc = 0.f;
#pragma unroll
    for (int j4 = 0; j4 < 8; j4++) {
      float4 pp = *(const float4*)&p[u][g * 32 + j4 * 4];   // wave-uniform: broadcast
      acc += pp.x * vreg[j4 * 4] + pp.y * vreg[j4 * 4 + 1] +
             pp.z * vreg[j4 * 4 + 2] + pp.w * vreg[j4 * 4 + 3];
    }
    part[g][u][d] = acc;
  }
  // softmax denominator partials: 136 threads each sum a 32-chunk of one u-row
  if (t < USEL * 4) {
    int u = t >> 2, ch = t & 3;
    float sum = 0.f;
#pragma unroll
    for (int jj = 0; jj < 32; jj++) sum += p[u][ch * 32 + jj];
    atomicAdd(&ssum[hb * USEL + u], sum);
  }
  __syncthreads();
  for (int idx = t; idx < USEL * DH; idx += 256) {
    int u = idx >> 6, dd = idx & 63;
    float sum = part[0][u][dd] + part[1][u][dd] + part[2][u][dd] + part[3][u][dd];
    atomicAdd(&delta_raw[((size_t)hb * USEL + u) * DH + dd], sum);
  }
}

// ---------------- k7: base[b,o] = sum_j tile(vmean)[j] * W[j,o] ----------------
__global__ __launch_bounds__(256) void k_base(const float* __restrict__ W,
                                              const float* __restrict__ vmean,
                                              float* __restrict__ base) {
  __shared__ float vm[DH];
  int b = blockIdx.y, hc = blockIdx.z;
  int o = blockIdx.x * 256 + threadIdx.x;
  if (threadIdx.x < DH) vm[threadIdx.x] = vmean[b * DH + threadIdx.x];
  __syncthreads();
  const float* Wr = W + (size_t)hc * DH * DM + o;
  float acc = 0.f;
#pragma unroll
  for (int d = 0; d < DH; d++) acc += vm[d] * Wr[(size_t)d * DM];
  atomicAdd(&base[b * DM + o], acc);
}

// ---------------- k8a: out[b,i,:] = base[b,:] + bproj  (dense fill) ----------------
__global__ __launch_bounds__(256) void k_fill(const float* __restrict__ base,
                                              const float* __restrict__ bproj,
                                              float* __restrict__ out) {
  int idx = blockIdx.x * 256 + threadIdx.x;        // float4 index
  int o4 = idx & (DM / 4 - 1);
  int b = idx >> 18;
  float4 bs = ((const float4*)base)[b * (DM / 4) + o4];
  float4 bp = ((const float4*)bproj)[o4];
  ((float4*)out)[idx] = make_float4(bs.x + bp.x, bs.y + bp.y, bs.z + bp.z, bs.w + bp.w);
}

// ------- k8b: one block per selected (h,b,u): out[b,i,:] += (raw/sum - vmean) @ W_h
__global__ __launch_bounds__(256) void k_corr(const float* __restrict__ W,
                                              const int* __restrict__ topidx,
                                              const float* __restrict__ delta_raw,
                                              const float* __restrict__ ssum,
                                              const float* __restrict__ vmean,
                                              float* __restrict__ out) {
  int u = blockIdx.x, hb = blockIdx.y;             // hb = h*BB + b
  int h = hb >> 1, b = hb & 1;
  int t = threadIdx.x;
  __shared__ float dl[DH];
  int i = topidx[hb * USEL + u];
  if (t < DH) {
    float inv = 1.0f / ssum[hb * USEL + u];
    dl[t] = delta_raw[((size_t)hb * USEL + u) * DH + t] * inv - vmean[b * DH + t];
  }
  __syncthreads();
  const float* Wh = W + (size_t)h * DH * DM;
  float* orow = out + ((size_t)b * LQ + i) * DM;
#pragma unroll
  for (int rep = 0; rep < 4; rep++) {
    int o = rep * 256 + t;
    float acc = 0.f;
#pragma unroll 16
    for (int d = 0; d < DH; d++) acc += dl[d] * Wh[(size_t)d * DM + o];
    atomicAdd(&orow[o], acc);                       // heads may share a row
  }
}

// ---------------- host ----------------
extern "C" void kernel_launch(void* const* d_in, const int* in_sizes, int n_in,
                              void* d_out, int out_size, void* d_ws, size_t ws_size,
                              hipStream_t stream) {
  const float* q  = (const float*)d_in[0];
  const float* k  = (const float*)d_in[1];
  const float* v  = (const float*)d_in[2];
  const float* W  = (const float*)d_in[3];
  const float* bp = (const float*)d_in[4];
  float* out = (float*)d_out;

  // S lives in d_out (8 MB): consumed by k_M/k_pv before k_fill overwrites it.
  float* S = out;

  // zeroed region: counts, base, kmean, vmean, delta_raw, ssum (atomic-accumulated)
  char* w = (char*)d_ws;
  unsigned* counts    = (unsigned*)w;         w += (size_t)NH * BB * LK * 4;          // 128 KB
  float*    base      = (float*)w;            w += (size_t)BB * DM * 4;               // 8 KB
  float*    kmean     = (float*)w;            w += (size_t)NH * BB * DH * 4;          // 8 KB
  float*    vmean     = (float*)w;            w += (size_t)BB * DH * 4;               // 512 B
  float*    delta_raw = (float*)w;            w += (size_t)NH * BB * USEL * DH * 4;   // 272 KB
  float*    ssum      = (float*)w;            w += (size_t)NH * BB * USEL * 4;        // 4.25 KB
  float*    M         = (float*)w;            w += (size_t)NH * BB * LQ * 4;          // 128 KB
  int*      topidx    = (int*)w;              w += (size_t)NH * BB * USEL * 4;        // 4.25 KB
  if ((size_t)(w - (char*)d_ws) > ws_size) return;

  const int ZW = NH * BB * LK + BB * DM + NH * BB * DH + BB * DH +
                 NH * BB * USEL * DH + NH * BB * USEL;
  k_zero  <<<(ZW + 255) / 256, 256, 0, stream>>>(counts, ZW);
  k_sample<<<dim3((USAMP + 255) / 256, NH), 256, 0, stream>>>(counts);
  k_means <<<dim3(NSLICE, NH * BB + BB), 256, 0, stream>>>(k, v, counts, kmean, vmean);
  k_scores<<<dim3(LK / 64, LQ / 64, BB), 256, 0, stream>>>(q, k, S);
  k_M     <<<dim3(LQ / 4, BB), 256, 0, stream>>>(q, S, counts, kmean, M);
  k_topk  <<<NH * BB, 64, 0, stream>>>(M, topidx);
  k_pv    <<<dim3(NJ, NH * BB), 256, 0, stream>>>(S, v, topidx, delta_raw, ssum);
  k_base  <<<dim3(DM / 256, BB, NH), 256, 0, stream>>>(W, vmean, base);
  k_fill  <<<(BB * LQ * DM / 4) / 256, 256, 0, stream>>>(base, bp, out);
  k_corr  <<<dim3(USEL, NH * BB), 256, 0, stream>>>(W, topidx, delta_raw, ssum, vmean, out);
}

// Round 10
// 178.162 us; speedup vs baseline: 1.0371x; 1.0371x over previous
//
#include <hip/hip_runtime.h>
#include <math.h>
#include <stdint.h>
#include <stddef.h>

// ProbSparse multi-head attention (Informer-style), fp32, MI355X.
// Heads share q,k,v; only the threefry-sampled key set differs per head.
// S (2x1024x1024 scores) lives in d_out, consumed (k_M, k_pv) before
// k_fill/k_corr overwrite d_out. No workspace buffer is assumed zeroed and
// there are no global atomics except k_corr's out-row adds: all partial
// accumulations are written per-slice and reduced on read.
// Softmax uses no max-shift: |S|/32 <= ~1.5 for N(0,1) inputs -> exp safe.

#define BB     2
#define LQ     1024
#define LK     1024
#define DH     64
#define NH     16
#define DM     1024
#define USEL   34
#define USAMP  7097
#define NSLICE 8          // j-slices in k_means
#define NJ     8          // j-slices in k_pv
#define JS     (LK / NJ)  // 128

#define THREEFRY_PARTITIONABLE 1

// ---------------- threefry2x32 (matches jax._src.prng) ----------------
__device__ __forceinline__ uint32_t rotl32(uint32_t x, int d) {
  return (x << d) | (x >> (32 - d));
}

__device__ __forceinline__ void threefry2x32(uint32_t k0, uint32_t k1,
                                             uint32_t x0, uint32_t x1,
                                             uint32_t& o0, uint32_t& o1) {
  uint32_t ks2 = k0 ^ k1 ^ 0x1BD11BDAu;
  x0 += k0; x1 += k1;
#define TFR(r) { x0 += x1; x1 = rotl32(x1, (r)); x1 ^= x0; }
  TFR(13) TFR(15) TFR(26) TFR(6)
  x0 += k1; x1 += ks2 + 1u;
  TFR(17) TFR(29) TFR(16) TFR(24)
  x0 += ks2; x1 += k0 + 2u;
  TFR(13) TFR(15) TFR(26) TFR(6)
  x0 += k0; x1 += k1 + 3u;
  TFR(17) TFR(29) TFR(16) TFR(24)
  x0 += k1; x1 += ks2 + 4u;
  TFR(13) TFR(15) TFR(26) TFR(6)
  x0 += ks2; x1 += k0 + 5u;
#undef TFR
  o0 = x0; o1 = x1;
}

// ---- k1: one block per (h,b): LDS histogram, overwrite counts (no zero, no
// ---- global atomics). 1024 threads, ~7 threefry each.
__global__ __launch_bounds__(1024) void k_sample(unsigned* __restrict__ counts) {
  int hb = blockIdx.x, h = hb >> 1, b = hb & 1;
  int t = threadIdx.x;
  __shared__ unsigned hist[LK];      // 4 KB
  hist[t] = 0u;
  // every thread derives the randint key (uniform, ~2 threefry)
  uint32_t sk0, sk1;
#if THREEFRY_PARTITIONABLE
  {
    uint32_t hk0, hk1;
    threefry2x32(0u, 42u, 0u, (uint32_t)h, hk0, hk1);   // head_keys = split (foldlike)
    threefry2x32(hk0, hk1, 0u, 1u, sk0, sk1);           // k2 = split(head_key)[1]
  }
#else
  {
    uint32_t hk0, hk1, a0, a1, b0_, b1_, c0_, c1_;
    int i0 = 2 * h, i1 = 2 * h + 1;
    if (i0 < 16) { threefry2x32(0u, 42u, (uint32_t)i0, (uint32_t)(i0 + 16), a0, a1); hk0 = a0; }
    else         { threefry2x32(0u, 42u, (uint32_t)(i0 - 16), (uint32_t)i0, a0, a1); hk0 = a1; }
    if (i1 < 16) { threefry2x32(0u, 42u, (uint32_t)i1, (uint32_t)(i1 + 16), a0, a1); hk1 = a0; }
    else         { threefry2x32(0u, 42u, (uint32_t)(i1 - 16), (uint32_t)i1, a0, a1); hk1 = a1; }
    threefry2x32(hk0, hk1, 0u, 2u, b0_, b1_);
    threefry2x32(hk0, hk1, 1u, 3u, c0_, c1_);
    sk0 = b1_; sk1 = c1_;
  }
#endif
  __syncthreads();
  for (int j = t; j < USAMP; j += 1024) {
    uint32_t o0, o1, bits;
#if THREEFRY_PARTITIONABLE
    threefry2x32(sk0, sk1, 0u, (uint32_t)(b * USAMP + j), o0, o1);
    bits = o0 ^ o1;
#else
    threefry2x32(sk0, sk1, (uint32_t)j, (uint32_t)(j + USAMP), o0, o1);
    bits = (b == 0) ? o0 : o1;
#endif
    // randint span=1024 divides 2^16 -> multiplier term = 0 -> idx = bits % 1024
    atomicAdd(&hist[bits & (LK - 1)], 1u);
  }
  __syncthreads();
  counts[(size_t)hb * LK + t] = hist[t];   // full overwrite, non-atomic
}

// ------- k2: kmean/vmean — j-sliced, float4, NON-atomic per-slice partials
// grid (NSLICE, NH*BB + BB); tasks 0..31 -> kmean_part, 32..33 -> vmean_part
__global__ __launch_bounds__(256) void k_means(const float* __restrict__ kk,
                                               const float* __restrict__ v,
                                               const unsigned* __restrict__ counts,
                                               float* __restrict__ kmean_part,
                                               float* __restrict__ vmean_part) {
  int task = blockIdx.y, s = blockIdx.x, t = threadIdx.x;
  int d4 = t & 15, jsub = t >> 4;               // 16 float4-lanes over d, 16 j-rows
  __shared__ float4 part[16][16];               // [jsub][d4]
  float4 acc = make_float4(0.f, 0.f, 0.f, 0.f);
  if (task < NH * BB) {
    int b = task & 1;
    const unsigned* cnt = counts + (size_t)task * LK;
    const float4* kb4 = (const float4*)(kk + (size_t)b * LK * DH);
#pragma unroll
    for (int jj = 0; jj < LK / (16 * NSLICE); jj++) {   // 8 independent loads in flight
      int j = s * (LK / NSLICE) + jsub + 16 * jj;
      float c = (float)cnt[j];
      float4 kv = kb4[j * 16 + d4];
      acc.x += c * kv.x; acc.y += c * kv.y; acc.z += c * kv.z; acc.w += c * kv.w;
    }
  } else {
    int b = task - NH * BB;
    const float4* vb4 = (const float4*)(v + (size_t)b * LK * DH);
#pragma unroll
    for (int jj = 0; jj < LK / (16 * NSLICE); jj++) {
      int j = s * (LK / NSLICE) + jsub + 16 * jj;
      float4 kv = vb4[j * 16 + d4];
      acc.x += kv.x; acc.y += kv.y; acc.z += kv.z; acc.w += kv.w;
    }
  }
  part[jsub][d4] = acc;
  __syncthreads();
  if (t < 16) {
    float4 sum = part[0][t];
#pragma unroll
    for (int x = 1; x < 16; x++) {
      float4 p = part[x][t];
      sum.x += p.x; sum.y += p.y; sum.z += p.z; sum.w += p.w;
    }
    if (task < NH * BB) {
      float* dst = kmean_part + ((size_t)s * NH * BB + task) * DH;
      const float sc = 1.0f / (float)USAMP;
      dst[t * 4 + 0] = sum.x * sc; dst[t * 4 + 1] = sum.y * sc;
      dst[t * 4 + 2] = sum.z * sc; dst[t * 4 + 3] = sum.w * sc;
    } else {
      float* dst = vmean_part + ((size_t)s * BB + (task - NH * BB)) * DH;
      const float sc = 1.0f / (float)LK;
      dst[t * 4 + 0] = sum.x * sc; dst[t * 4 + 1] = sum.y * sc;
      dst[t * 4 + 2] = sum.z * sc; dst[t * 4 + 3] = sum.w * sc;
    }
  }
}

// ------- k3: S[b,i,j] = q_i . k_j — transposed LDS, outer-product inner loop
__global__ __launch_bounds__(256) void k_scores(const float* __restrict__ q,
                                                const float* __restrict__ k,
                                                float* __restrict__ S) {
  __shared__ float Qt[DH][68];
  __shared__ float Kt[DH][68];
  int b = blockIdx.z;
  int i0 = blockIdx.y * 64, j0 = blockIdx.x * 64;
  int t = threadIdx.x;
  const float* qb = q + ((size_t)b * LQ + i0) * DH;
  const float* kb = k + ((size_t)b * LK + j0) * DH;
#pragma unroll
  for (int rep = 0; rep < 4; rep++) {
    int lin = (rep * 256 + t) * 4;
    int r = lin >> 6, c = lin & 63;
    float4 qv = *(const float4*)(qb + (size_t)r * DH + c);
    float4 kv = *(const float4*)(kb + (size_t)r * DH + c);
    Qt[c][r] = qv.x; Qt[c + 1][r] = qv.y; Qt[c + 2][r] = qv.z; Qt[c + 3][r] = qv.w;
    Kt[c][r] = kv.x; Kt[c + 1][r] = kv.y; Kt[c + 2][r] = kv.z; Kt[c + 3][r] = kv.w;
  }
  __syncthreads();
  int tx = t & 15, ty = t >> 4;
  float acc[4][4] = {};
#pragma unroll 8
  for (int d = 0; d < DH; d++) {
    float4 av = *(const float4*)&Qt[d][ty * 4];
    float4 bv = *(const float4*)&Kt[d][tx * 4];
    acc[0][0] += av.x * bv.x; acc[0][1] += av.x * bv.y; acc[0][2] += av.x * bv.z; acc[0][3] += av.x * bv.w;
    acc[1][0] += av.y * bv.x; acc[1][1] += av.y * bv.y; acc[1][2] += av.y * bv.z; acc[1][3] += av.y * bv.w;
    acc[2][0] += av.z * bv.x; acc[2][1] += av.z * bv.y; acc[2][2] += av.z * bv.z; acc[2][3] += av.z * bv.w;
    acc[3][0] += av.w * bv.x; acc[3][1] += av.w * bv.y; acc[3][2] += av.w * bv.z; acc[3][3] += av.w * bv.w;
  }
  float* Sb = S + ((size_t)b * LQ + i0) * LK + j0;
#pragma unroll
  for (int r = 0; r < 4; r++) {
    *(float4*)(Sb + (size_t)(ty * 4 + r) * LK + tx * 4) =
        make_float4(acc[r][0], acc[r][1], acc[r][2], acc[r][3]);
  }
}

// ------- k4: M[h,b,i] = max_{sampled j} S[i,j] - q_i.kmean[h,b] — one S pass,
// ------- kmean partials reduced once into LDS
__global__ __launch_bounds__(256) void k_M(const float* __restrict__ q,
                                           const float* __restrict__ S,
                                           const unsigned* __restrict__ counts,
                                           const float* __restrict__ kmean_part,
                                           float* __restrict__ M) {
  int b = blockIdx.y;
  __shared__ uint32_t mask[NH][LK / 32];   // 2 KB
  __shared__ float kmean_s[NH][DH];        // 4 KB
  int t = threadIdx.x;
  for (int w = t; w < NH * (LK / 32); w += 256) {
    int h = w >> 5, blk = w & 31;
    const unsigned* cnt = counts + ((size_t)h * BB + b) * LK + blk * 32;
    uint32_t m = 0;
    for (int z = 0; z < 32; z++) m |= (cnt[z] != 0u ? 1u : 0u) << z;
    mask[h][blk] = m;
  }
  for (int idx = t; idx < NH * DH; idx += 256) {
    int h = idx >> 6, d = idx & 63;
    float sum = 0.f;
#pragma unroll
    for (int sl = 0; sl < NSLICE; sl++)
      sum += kmean_part[((size_t)sl * NH * BB + h * BB + b) * DH + d];
    kmean_s[h][d] = sum;
  }
  __syncthreads();
  int lane = t & 63, w4 = t >> 6;
  int i = blockIdx.x * 4 + w4;
  const float* Srow = S + ((size_t)b * LQ + i) * LK;
  float mx[NH];
#pragma unroll
  for (int h = 0; h < NH; h++) mx[h] = -INFINITY;
  for (int j = lane; j < LK; j += 64) {
    float s = Srow[j];
#pragma unroll
    for (int h = 0; h < NH; h++) {
      bool on = (mask[h][j >> 5] >> (j & 31)) & 1u;
      mx[h] = fmaxf(mx[h], on ? s : -INFINITY);
    }
  }
#pragma unroll
  for (int h = 0; h < NH; h++) {
#pragma unroll
    for (int off = 32; off > 0; off >>= 1) mx[h] = fmaxf(mx[h], __shfl_xor(mx[h], off));
  }
  float qv = q[((size_t)b * LQ + i) * DH + lane];  // lane == d (DH==64)
#pragma unroll
  for (int h = 0; h < NH; h++) {
    float p = qv * kmean_s[h][lane];
#pragma unroll
    for (int off = 32; off > 0; off >>= 1) p += __shfl_xor(p, off);
    mx[h] -= p;
  }
  if (lane == 0) {
#pragma unroll
    for (int h = 0; h < NH; h++) M[((size_t)h * BB + b) * LQ + i] = mx[h];
  }
}

// ---------------- k5: top-34 per (h,b) — shfl-based argmax (256 thr) ----------------
__global__ __launch_bounds__(256) void k_topk(const float* __restrict__ M,
                                              int* __restrict__ topidx) {
  int hb = blockIdx.x, t = threadIdx.x;
  __shared__ float vals[LQ];
  __shared__ float wv[4];
  __shared__ int   wi[4];
  for (int i = t; i < LQ; i += 256) vals[i] = M[(size_t)hb * LQ + i];
  __syncthreads();
  int lane = t & 63, w = t >> 6;
  for (int u = 0; u < USEL; u++) {
    float bv = -INFINITY; int bi = 0x7fffffff;
#pragma unroll
    for (int r = 0; r < 4; r++) {     // ascending idx + strict '>' => lowest idx on tie
      int i = r * 256 + t;
      float x = vals[i];
      if (x > bv) { bv = x; bi = i; }
    }
#pragma unroll
    for (int off = 32; off > 0; off >>= 1) {
      float ov = __shfl_xor(bv, off);
      int   oi = __shfl_xor(bi, off);
      if (ov > bv || (ov == bv && oi < bi)) { bv = ov; bi = oi; }
    }
    if (lane == 0) { wv[w] = bv; wi[w] = bi; }
    __syncthreads();
    if (t == 0) {
      float fv = wv[0]; int fi = wi[0];
#pragma unroll
      for (int x = 1; x < 4; x++)
        if (wv[x] > fv || (wv[x] == fv && wi[x] < fi)) { fv = wv[x]; fi = wi[x]; }
      topidx[hb * USEL + u] = fi;
      vals[fi] = -INFINITY;
    }
    __syncthreads();
  }
}

// ------- k6: PV j-sliced — NON-atomic per-slice partials for PV and ssum
// grid (NJ, NH*BB). No max-shift. LDS-staged p, register-staged v.
__global__ __launch_bounds__(256) void k_pv(const float* __restrict__ S,
                                            const float* __restrict__ v,
                                            const int* __restrict__ topidx,
                                            float* __restrict__ delta_part,
                                            float* __restrict__ ssum_part) {
  int hb = blockIdx.y, s = blockIdx.x, b = hb & 1;
  int t = threadIdx.x, d = t & 63, g = t >> 6;
  __shared__ float p[USEL][JS];        // 17 KB
  __shared__ float part[4][USEL][DH];  // 34.8 KB
  for (int idx = t; idx < USEL * JS; idx += 256) {
    int u = idx >> 7, jj = idx & (JS - 1);
    int i = topidx[hb * USEL + u];
    float xs = S[((size_t)b * LQ + i) * LK + s * JS + jj];
    p[u][jj] = expf(xs * 0.03125f);    // 1/sqrt(1024) = 1/32 exactly
  }
  __syncthreads();
  // each wave owns 32 contiguous jj; v values held in registers
  float vreg[32];
  const float* vb = v + ((size_t)b * LK + s * JS + g * 32) * DH + d;
#pragma unroll
  for (int jj = 0; jj < 32; jj++) vreg[jj] = vb[(size_t)jj * DH];
  for (int u = 0; u < USEL; u++) {
    float acc = 0.f;
#pragma unroll
    for (int j4 = 0; j4 < 8; j4++) {
      float4 pp = *(const float4*)&p[u][g * 32 + j4 * 4];   // wave-uniform: broadcast
      acc += pp.x * vreg[j4 * 4] + pp.y * vreg[j4 * 4 + 1] +
             pp.z * vreg[j4 * 4 + 2] + pp.w * vreg[j4 * 4 + 3];
    }
    part[g][u][d] = acc;
  }
  // softmax denominator: 136 threads each sum one 32-chunk, plain store
  if (t < USEL * 4) {
    int u = t >> 2, ch = t & 3;
    float sum = 0.f;
#pragma unroll
    for (int jj = 0; jj < 32; jj++) sum += p[u][ch * 32 + jj];
    ssum_part[(((size_t)s * NH * BB + hb) * USEL + u) * 4 + ch] = sum;
  }
  __syncthreads();
  for (int idx = t; idx < USEL * DH; idx += 256) {
    int u = idx >> 6, dd = idx & 63;
    float sum = part[0][u][dd] + part[1][u][dd] + part[2][u][dd] + part[3][u][dd];
    delta_part[(((size_t)s * NH * BB + hb) * USEL + u) * DH + dd] = sum;
  }
}

// ------- k7: base_part[hc][b][o] = vmean . W_hc[:,o]  (non-atomic) ----------------
__global__ __launch_bounds__(256) void k_base(const float* __restrict__ W,
                                              const float* __restrict__ vmean_part,
                                              float* __restrict__ base_part) {
  __shared__ float vm[DH];
  int b = blockIdx.y, hc = blockIdx.z;
  int o = blockIdx.x * 256 + threadIdx.x;
  if (threadIdx.x < DH) {
    float s = 0.f;
#pragma unroll
    for (int sl = 0; sl < NSLICE; sl++)
      s += vmean_part[((size_t)sl * BB + b) * DH + threadIdx.x];
    vm[threadIdx.x] = s;
  }
  __syncthreads();
  const float* Wr = W + (size_t)hc * DH * DM + o;
  float acc = 0.f;
#pragma unroll
  for (int d = 0; d < DH; d++) acc += vm[d] * Wr[(size_t)d * DM];
  base_part[((size_t)hc * BB + b) * DM + o] = acc;
}

// ------- k8a: out[b,i,:] = sum_hc base_part + bproj  (dense fill) ----------------
__global__ __launch_bounds__(256) void k_fill(const float* __restrict__ base_part,
                                              const float* __restrict__ bproj,
                                              float* __restrict__ out) {
  int idx = blockIdx.x * 256 + threadIdx.x;        // float4 index
  int o4 = idx & (DM / 4 - 1);
  int b = (idx >> 18) & 1;                         // idx / (LQ*DM/4)
  float4 bs = ((const float4*)bproj)[o4];
#pragma unroll
  for (int hc = 0; hc < NH; hc++) {
    float4 p = ((const float4*)base_part)[((size_t)hc * BB + b) * (DM / 4) + o4];
    bs.x += p.x; bs.y += p.y; bs.z += p.z; bs.w += p.w;
  }
  ((float4*)out)[idx] = bs;
}

// ------- k8b: one block per (h,b,u): out[b,i,:] += (sum_s delta/sum_s ssum - vmean) @ W_h
__global__ __launch_bounds__(256) void k_corr(const float* __restrict__ W,
                                              const int* __restrict__ topidx,
                                              const float* __restrict__ delta_part,
                                              const float* __restrict__ ssum_part,
                                              const float* __restrict__ vmean_part,
                                              float* __restrict__ out) {
  int u = blockIdx.x, hb = blockIdx.y;             // hb = h*BB + b
  int h = hb >> 1, b = hb & 1;
  int t = threadIdx.x;
  __shared__ float dl[DH];
  int i = topidx[hb * USEL + u];
  if (t < DH) {
    float ss = 0.f, dr = 0.f, vm = 0.f;
#pragma unroll
    for (int sl = 0; sl < NJ; sl++) {
      const float* sp = ssum_part + (((size_t)sl * NH * BB + hb) * USEL + u) * 4;
      ss += sp[0] + sp[1] + sp[2] + sp[3];
      dr += delta_part[(((size_t)sl * NH * BB + hb) * USEL + u) * DH + t];
    }
#pragma unroll
    for (int sl = 0; sl < NSLICE; sl++)
      vm += vmean_part[((size_t)sl * BB + b) * DH + t];
    dl[t] = dr / ss - vm;
  }
  __syncthreads();
  const float* Wh = W + (size_t)h * DH * DM;
  float* orow = out + ((size_t)b * LQ + i) * DM;
#pragma unroll
  for (int rep = 0; rep < 4; rep++) {
    int o = rep * 256 + t;
    float acc = 0.f;
#pragma unroll 16
    for (int d = 0; d < DH; d++) acc += dl[d] * Wh[(size_t)d * DM + o];
    atomicAdd(&orow[o], acc);                       // heads may share a row
  }
}

// ---------------- host ----------------
extern "C" void kernel_launch(void* const* d_in, const int* in_sizes, int n_in,
                              void* d_out, int out_size, void* d_ws, size_t ws_size,
                              hipStream_t stream) {
  const float* q  = (const float*)d_in[0];
  const float* k  = (const float*)d_in[1];
  const float* v  = (const float*)d_in[2];
  const float* W  = (const float*)d_in[3];
  const float* bp = (const float*)d_in[4];
  float* out = (float*)d_out;

  // S lives in d_out (8 MB): consumed by k_M/k_pv before k_fill overwrites it.
  float* S = out;

  // workspace: every buffer fully overwritten before read — nothing needs zeroing
  char* w = (char*)d_ws;
  unsigned* counts     = (unsigned*)w;  w += (size_t)NH * BB * LK * 4;                 // 128 KB
  float*    kmean_part = (float*)w;     w += (size_t)NSLICE * NH * BB * DH * 4;        // 64 KB
  float*    vmean_part = (float*)w;     w += (size_t)NSLICE * BB * DH * 4;             // 4 KB
  float*    base_part  = (float*)w;     w += (size_t)NH * BB * DM * 4;                 // 128 KB
  float*    delta_part = (float*)w;     w += (size_t)NJ * NH * BB * USEL * DH * 4;     // 2.23 MB
  float*    ssum_part  = (float*)w;     w += (size_t)NJ * NH * BB * USEL * 4 * 4;      // 139 KB
  float*    M          = (float*)w;     w += (size_t)NH * BB * LQ * 4;                 // 128 KB
  int*      topidx     = (int*)w;       w += (size_t)NH * BB * USEL * 4;               // 4.25 KB
  if ((size_t)(w - (char*)d_ws) > ws_size) return;

  k_sample<<<NH * BB, 1024, 0, stream>>>(counts);
  k_means <<<dim3(NSLICE, NH * BB + BB), 256, 0, stream>>>(k, v, counts, kmean_part, vmean_part);
  k_scores<<<dim3(LK / 64, LQ / 64, BB), 256, 0, stream>>>(q, k, S);
  k_M     <<<dim3(LQ / 4, BB), 256, 0, stream>>>(q, S, counts, kmean_part, M);
  k_topk  <<<NH * BB, 256, 0, stream>>>(M, topidx);
  k_pv    <<<dim3(NJ, NH * BB), 256, 0, stream>>>(S, v, topidx, delta_part, ssum_part);
  k_base  <<<dim3(DM / 256, BB, NH), 256, 0, stream>>>(W, vmean_part, base_part);
  k_fill  <<<(BB * LQ * DM / 4) / 256, 256, 0, stream>>>(base_part, bp, out);
  k_corr  <<<dim3(USEL, NH * BB), 256, 0, stream>>>(W, topidx, delta_part, ssum_part, vmean_part, out);
}

// Round 11
// 158.139 us; speedup vs baseline: 1.1684x; 1.1266x over previous
//
#include <hip/hip_runtime.h>
#include <math.h>
#include <stdint.h>
#include <stddef.h>

// ProbSparse multi-head attention (Informer-style), fp32, MI355X.
// 5-launch structure: independent kernels merged into role-switched dispatches.
// L1: scores GEMM ∪ sample+kmean ∪ vmean     (546 blocks)
// L2: M (masked max) ∪ base GEMV             (640 blocks)
// L3: topk ∪ dense out fill                  (2080 blocks)
// L4: pv (j-sliced PV partials)              (256 blocks)
// L5: corr (rank-64 row corrections)         (1088 blocks)
// S lives in d_ws. No buffer is assumed zeroed; no global atomics except
// k_corr's out-row adds. Softmax has no max-shift (|S|/32 <= ~1.5).

#define BB     2
#define LQ     1024
#define LK     1024
#define DH     64
#define NH     16
#define DM     1024
#define USEL   34
#define USAMP  7097
#define NJ     8          // j-slices in k_pv
#define JS     (LK / NJ)  // 128
#define NSC    512        // scores blocks in L1
#define NMB    512        // M blocks in L2
#define NTK    32         // topk blocks in L3

#define THREEFRY_PARTITIONABLE 1

// ---------------- threefry2x32 (matches jax._src.prng) ----------------
__device__ __forceinline__ uint32_t rotl32(uint32_t x, int d) {
  return (x << d) | (x >> (32 - d));
}

__device__ __forceinline__ void threefry2x32(uint32_t k0, uint32_t k1,
                                             uint32_t x0, uint32_t x1,
                                             uint32_t& o0, uint32_t& o1) {
  uint32_t ks2 = k0 ^ k1 ^ 0x1BD11BDAu;
  x0 += k0; x1 += k1;
#define TFR(r) { x0 += x1; x1 = rotl32(x1, (r)); x1 ^= x0; }
  TFR(13) TFR(15) TFR(26) TFR(6)
  x0 += k1; x1 += ks2 + 1u;
  TFR(17) TFR(29) TFR(16) TFR(24)
  x0 += ks2; x1 += k0 + 2u;
  TFR(13) TFR(15) TFR(26) TFR(6)
  x0 += k0; x1 += k1 + 3u;
  TFR(17) TFR(29) TFR(16) TFR(24)
  x0 += k1; x1 += ks2 + 4u;
  TFR(13) TFR(15) TFR(26) TFR(6)
  x0 += ks2; x1 += k0 + 5u;
#undef TFR
  o0 = x0; o1 = x1;
}

__device__ __forceinline__ void randint_key(int h, uint32_t& sk0, uint32_t& sk1) {
#if THREEFRY_PARTITIONABLE
  uint32_t hk0, hk1;
  threefry2x32(0u, 42u, 0u, (uint32_t)h, hk0, hk1);   // head_keys = split (foldlike)
  threefry2x32(hk0, hk1, 0u, 1u, sk0, sk1);           // k2 = split(head_key)[1]
#else
  uint32_t hk0, hk1, a0, a1, b0_, b1_, c0_, c1_;
  int i0 = 2 * h, i1 = 2 * h + 1;
  if (i0 < 16) { threefry2x32(0u, 42u, (uint32_t)i0, (uint32_t)(i0 + 16), a0, a1); hk0 = a0; }
  else         { threefry2x32(0u, 42u, (uint32_t)(i0 - 16), (uint32_t)i0, a0, a1); hk0 = a1; }
  if (i1 < 16) { threefry2x32(0u, 42u, (uint32_t)i1, (uint32_t)(i1 + 16), a0, a1); hk1 = a0; }
  else         { threefry2x32(0u, 42u, (uint32_t)(i1 - 16), (uint32_t)i1, a0, a1); hk1 = a1; }
  threefry2x32(hk0, hk1, 0u, 2u, b0_, b1_);
  threefry2x32(hk0, hk1, 1u, 3u, c0_, c1_);
  sk0 = b1_; sk1 = c1_;
#endif
}

// =================== L1: scores ∪ sample+kmean ∪ vmean ===================
// bx < NSC: S-tile GEMM. bx in [NSC, NSC+32): hist+mask+kmean for hb.
// bx in [NSC+32, NSC+34): vmean for b.
__global__ __launch_bounds__(256) void k_prep_scores(const float* __restrict__ q,
                                                     const float* __restrict__ kk,
                                                     const float* __restrict__ v,
                                                     float* __restrict__ S,
                                                     unsigned* __restrict__ mask_g,
                                                     float* __restrict__ kmean,
                                                     float* __restrict__ vmean) {
  __shared__ __align__(16) char smem[34816];
  int bx = blockIdx.x, t = threadIdx.x;
  if (bx < NSC) {
    // ---- scores role: transposed LDS, outer-product inner loop ----
    float (*Qt)[68] = (float (*)[68])smem;                 // 17408 B
    float (*Kt)[68] = (float (*)[68])(smem + 17408);       // 17408 B
    int b = bx >> 8, it = (bx >> 4) & 15, jt = bx & 15;
    int i0 = it * 64, j0 = jt * 64;
    const float* qb = q + ((size_t)b * LQ + i0) * DH;
    const float* kb = kk + ((size_t)b * LK + j0) * DH;
#pragma unroll
    for (int rep = 0; rep < 4; rep++) {
      int lin = (rep * 256 + t) * 4;
      int r = lin >> 6, c = lin & 63;
      float4 qv = *(const float4*)(qb + (size_t)r * DH + c);
      float4 kv = *(const float4*)(kb + (size_t)r * DH + c);
      Qt[c][r] = qv.x; Qt[c + 1][r] = qv.y; Qt[c + 2][r] = qv.z; Qt[c + 3][r] = qv.w;
      Kt[c][r] = kv.x; Kt[c + 1][r] = kv.y; Kt[c + 2][r] = kv.z; Kt[c + 3][r] = kv.w;
    }
    __syncthreads();
    int tx = t & 15, ty = t >> 4;
    float acc[4][4] = {};
#pragma unroll 8
    for (int d = 0; d < DH; d++) {
      float4 av = *(const float4*)&Qt[d][ty * 4];
      float4 bv = *(const float4*)&Kt[d][tx * 4];
      acc[0][0] += av.x * bv.x; acc[0][1] += av.x * bv.y; acc[0][2] += av.x * bv.z; acc[0][3] += av.x * bv.w;
      acc[1][0] += av.y * bv.x; acc[1][1] += av.y * bv.y; acc[1][2] += av.y * bv.z; acc[1][3] += av.y * bv.w;
      acc[2][0] += av.z * bv.x; acc[2][1] += av.z * bv.y; acc[2][2] += av.z * bv.z; acc[2][3] += av.z * bv.w;
      acc[3][0] += av.w * bv.x; acc[3][1] += av.w * bv.y; acc[3][2] += av.w * bv.z; acc[3][3] += av.w * bv.w;
    }
    float* Sb = S + ((size_t)b * LQ + i0) * LK + j0;
#pragma unroll
    for (int r = 0; r < 4; r++) {
      *(float4*)(Sb + (size_t)(ty * 4 + r) * LK + tx * 4) =
          make_float4(acc[r][0], acc[r][1], acc[r][2], acc[r][3]);
    }
  } else if (bx < NSC + NH * BB) {
    // ---- sample + mask + kmean role (one block per hb) ----
    int hb = bx - NSC, h = hb >> 1, b = hb & 1;
    unsigned* hist = (unsigned*)smem;                       // 4096 B
    float4 (*part)[16] = (float4 (*)[16])(smem + 4096);     // 4096 B
    hist[t] = 0u; hist[t + 256] = 0u; hist[t + 512] = 0u; hist[t + 768] = 0u;
    uint32_t sk0, sk1;
    randint_key(h, sk0, sk1);                               // uniform across threads
    __syncthreads();
    for (int j = t; j < USAMP; j += 256) {
      uint32_t o0, o1, bits;
#if THREEFRY_PARTITIONABLE
      threefry2x32(sk0, sk1, 0u, (uint32_t)(b * USAMP + j), o0, o1);
      bits = o0 ^ o1;
#else
      threefry2x32(sk0, sk1, (uint32_t)j, (uint32_t)(j + USAMP), o0, o1);
      bits = (b == 0) ? o0 : o1;
#endif
      // randint span=1024 divides 2^16 -> multiplier term = 0 -> idx = bits % 1024
      atomicAdd(&hist[bits & (LK - 1)], 1u);
    }
    __syncthreads();
    if (t < LK / 32) {
      uint32_t m = 0;
      for (int z = 0; z < 32; z++) m |= (hist[t * 32 + z] != 0u ? 1u : 0u) << z;
      mask_g[hb * (LK / 32) + t] = m;
    }
    // kmean (count-weighted) — float4 lanes over d, 16 j-rows
    int d4 = t & 15, jsub = t >> 4;
    const float4* kb4 = (const float4*)(kk + (size_t)b * LK * DH);
    float4 acc = make_float4(0.f, 0.f, 0.f, 0.f);
#pragma unroll 8
    for (int jj = 0; jj < LK / 16; jj++) {
      int j = jsub + 16 * jj;
      float c = (float)hist[j];
      float4 kv = kb4[j * 16 + d4];
      acc.x += c * kv.x; acc.y += c * kv.y; acc.z += c * kv.z; acc.w += c * kv.w;
    }
    part[jsub][d4] = acc;
    __syncthreads();
    if (t < 16) {
      float4 sum = part[0][t];
#pragma unroll
      for (int x = 1; x < 16; x++) {
        float4 p = part[x][t];
        sum.x += p.x; sum.y += p.y; sum.z += p.z; sum.w += p.w;
      }
      const float sc = 1.0f / (float)USAMP;
      float* dst = kmean + (size_t)hb * DH;
      dst[t * 4 + 0] = sum.x * sc; dst[t * 4 + 1] = sum.y * sc;
      dst[t * 4 + 2] = sum.z * sc; dst[t * 4 + 3] = sum.w * sc;
    }
  } else {
    // ---- vmean role (one block per b) ----
    int b = bx - NSC - NH * BB;
    float4 (*part)[16] = (float4 (*)[16])smem;
    int d4 = t & 15, jsub = t >> 4;
    const float4* vb4 = (const float4*)(v + (size_t)b * LK * DH);
    float4 acc = make_float4(0.f, 0.f, 0.f, 0.f);
#pragma unroll 8
    for (int jj = 0; jj < LK / 16; jj++) {
      int j = jsub + 16 * jj;
      float4 kv = vb4[j * 16 + d4];
      acc.x += kv.x; acc.y += kv.y; acc.z += kv.z; acc.w += kv.w;
    }
    part[jsub][d4] = acc;
    __syncthreads();
    if (t < 16) {
      float4 sum = part[0][t];
#pragma unroll
      for (int x = 1; x < 16; x++) {
        float4 p = part[x][t];
        sum.x += p.x; sum.y += p.y; sum.z += p.z; sum.w += p.w;
      }
      const float sc = 1.0f / (float)LK;
      float* dst = vmean + (size_t)b * DH;
      dst[t * 4 + 0] = sum.x * sc; dst[t * 4 + 1] = sum.y * sc;
      dst[t * 4 + 2] = sum.z * sc; dst[t * 4 + 3] = sum.w * sc;
    }
  }
}

// =================== L2: M (masked max) ∪ base GEMV ===================
// bx < NMB: M role (iblk = bx&255, b = bx>>8). Else base: idx = bx-NMB,
// o-tile = idx&3, b = (idx>>2)&1, hc = idx>>3.
__global__ __launch_bounds__(256) void k_M_base(const float* __restrict__ q,
                                                const float* __restrict__ S,
                                                const unsigned* __restrict__ mask_g,
                                                const float* __restrict__ kmean,
                                                const float* __restrict__ vmean,
                                                const float* __restrict__ W,
                                                float* __restrict__ M,
                                                float* __restrict__ base_part) {
  __shared__ __align__(16) char smem[6400];
  int bx = blockIdx.x, t = threadIdx.x;
  if (bx < NMB) {
    int b = bx >> 8, iblk = bx & 255;
    uint32_t (*mask)[LK / 32] = (uint32_t (*)[LK / 32])smem;      // 2048 B
    float (*kmean_s)[DH] = (float (*)[DH])(smem + 2048);          // 4096 B
    for (int w = t; w < NH * (LK / 32); w += 256) {
      int h = w >> 5, blk = w & 31;
      mask[h][blk] = mask_g[(size_t)(h * BB + b) * (LK / 32) + blk];
    }
    for (int idx = t; idx < NH * DH; idx += 256) {
      int h = idx >> 6, d = idx & 63;
      kmean_s[h][d] = kmean[(size_t)(h * BB + b) * DH + d];
    }
    __syncthreads();
    int lane = t & 63, w4 = t >> 6;
    int i = iblk * 4 + w4;
    const float* Srow = S + ((size_t)b * LQ + i) * LK;
    float mx[NH];
#pragma unroll
    for (int h = 0; h < NH; h++) mx[h] = -INFINITY;
    for (int j = lane; j < LK; j += 64) {
      float s = Srow[j];
#pragma unroll
      for (int h = 0; h < NH; h++) {
        bool on = (mask[h][j >> 5] >> (j & 31)) & 1u;
        mx[h] = fmaxf(mx[h], on ? s : -INFINITY);
      }
    }
#pragma unroll
    for (int h = 0; h < NH; h++) {
#pragma unroll
      for (int off = 32; off > 0; off >>= 1) mx[h] = fmaxf(mx[h], __shfl_xor(mx[h], off));
    }
    float qv = q[((size_t)b * LQ + i) * DH + lane];  // lane == d (DH==64)
#pragma unroll
    for (int h = 0; h < NH; h++) {
      float p = qv * kmean_s[h][lane];
#pragma unroll
      for (int off = 32; off > 0; off >>= 1) p += __shfl_xor(p, off);
      mx[h] -= p;
    }
    if (lane == 0) {
#pragma unroll
      for (int h = 0; h < NH; h++) M[((size_t)h * BB + b) * LQ + i] = mx[h];
    }
  } else {
    int idx = bx - NMB;
    int ob = idx & 3, b = (idx >> 2) & 1, hc = idx >> 3;
    float* vm = (float*)smem;
    if (t < DH) vm[t] = vmean[b * DH + t];
    __syncthreads();
    int o = ob * 256 + t;
    const float* Wr = W + (size_t)hc * DH * DM + o;
    float acc = 0.f;
#pragma unroll
    for (int d = 0; d < DH; d++) acc += vm[d] * Wr[(size_t)d * DM];
    base_part[((size_t)hc * BB + b) * DM + o] = acc;
  }
}

// =================== L3: topk ∪ dense fill ===================
__global__ __launch_bounds__(256) void k_topk_fill(const float* __restrict__ M,
                                                   int* __restrict__ topidx,
                                                   const float* __restrict__ base_part,
                                                   const float* __restrict__ bproj,
                                                   float* __restrict__ out) {
  __shared__ __align__(16) char smem[4160];
  int bx = blockIdx.x, t = threadIdx.x;
  if (bx < NTK) {
    int hb = bx;
    float* vals = (float*)smem;                 // 4096 B
    float* wv = (float*)(smem + 4096);          // 16 B
    int* wi = (int*)(smem + 4112);              // 16 B
    for (int i = t; i < LQ; i += 256) vals[i] = M[(size_t)hb * LQ + i];
    __syncthreads();
    int lane = t & 63, w = t >> 6;
    for (int u = 0; u < USEL; u++) {
      float bv = -INFINITY; int bi = 0x7fffffff;
#pragma unroll
      for (int r = 0; r < 4; r++) {     // ascending idx + strict '>' => lowest idx on tie
        int i = r * 256 + t;
        float x = vals[i];
        if (x > bv) { bv = x; bi = i; }
      }
#pragma unroll
      for (int off = 32; off > 0; off >>= 1) {
        float ov = __shfl_xor(bv, off);
        int   oi = __shfl_xor(bi, off);
        if (ov > bv || (ov == bv && oi < bi)) { bv = ov; bi = oi; }
      }
      if (lane == 0) { wv[w] = bv; wi[w] = bi; }
      __syncthreads();
      if (t == 0) {
        float fv = wv[0]; int fi = wi[0];
#pragma unroll
        for (int x = 1; x < 4; x++)
          if (wv[x] > fv || (wv[x] == fv && wi[x] < fi)) { fv = wv[x]; fi = wi[x]; }
        topidx[hb * USEL + u] = fi;
        vals[fi] = -INFINITY;
      }
      __syncthreads();
    }
  } else {
    int idx = (bx - NTK) * 256 + t;              // float4 index
    int o4 = idx & (DM / 4 - 1);
    int b = (idx >> 18) & 1;                     // idx / (LQ*DM/4)
    float4 bs = ((const float4*)bproj)[o4];
#pragma unroll
    for (int hc = 0; hc < NH; hc++) {
      float4 p = ((const float4*)base_part)[((size_t)hc * BB + b) * (DM / 4) + o4];
      bs.x += p.x; bs.y += p.y; bs.z += p.z; bs.w += p.w;
    }
    ((float4*)out)[idx] = bs;
  }
}

// =================== L4: PV j-sliced, non-atomic partials ===================
__global__ __launch_bounds__(256) void k_pv(const float* __restrict__ S,
                                            const float* __restrict__ v,
                                            const int* __restrict__ topidx,
                                            float* __restrict__ delta_part,
                                            float* __restrict__ ssum_part) {
  int hb = blockIdx.y, s = blockIdx.x, b = hb & 1;
  int t = threadIdx.x, d = t & 63, g = t >> 6;
  __shared__ float p[USEL][JS];        // 17 KB
  __shared__ float part[4][USEL][DH];  // 34.8 KB
  for (int idx = t; idx < USEL * JS; idx += 256) {
    int u = idx >> 7, jj = idx & (JS - 1);
    int i = topidx[hb * USEL + u];
    float xs = S[((size_t)b * LQ + i) * LK + s * JS + jj];
    p[u][jj] = expf(xs * 0.03125f);    // 1/sqrt(1024) = 1/32 exactly
  }
  __syncthreads();
  float vreg[32];
  const float* vb = v + ((size_t)b * LK + s * JS + g * 32) * DH + d;
#pragma unroll
  for (int jj = 0; jj < 32; jj++) vreg[jj] = vb[(size_t)jj * DH];
  for (int u = 0; u < USEL; u++) {
    float acc = 0.f;
#pragma unroll
    for (int j4 = 0; j4 < 8; j4++) {
      float4 pp = *(const float4*)&p[u][g * 32 + j4 * 4];   // wave-uniform: broadcast
      acc += pp.x * vreg[j4 * 4] + pp.y * vreg[j4 * 4 + 1] +
             pp.z * vreg[j4 * 4 + 2] + pp.w * vreg[j4 * 4 + 3];
    }
    part[g][u][d] = acc;
  }
  if (t < USEL * 4) {
    int u = t >> 2, ch = t & 3;
    float sum = 0.f;
#pragma unroll
    for (int jj = 0; jj < 32; jj++) sum += p[u][ch * 32 + jj];
    ssum_part[(((size_t)s * NH * BB + hb) * USEL + u) * 4 + ch] = sum;
  }
  __syncthreads();
  for (int idx = t; idx < USEL * DH; idx += 256) {
    int u = idx >> 6, dd = idx & 63;
    float sum = part[0][u][dd] + part[1][u][dd] + part[2][u][dd] + part[3][u][dd];
    delta_part[(((size_t)s * NH * BB + hb) * USEL + u) * DH + dd] = sum;
  }
}

// =================== L5: per-(h,b,u) rank-64 correction ===================
__global__ __launch_bounds__(256) void k_corr(const float* __restrict__ W,
                                              const int* __restrict__ topidx,
                                              const float* __restrict__ delta_part,
                                              const float* __restrict__ ssum_part,
                                              const float* __restrict__ vmean,
                                              float* __restrict__ out) {
  int u = blockIdx.x, hb = blockIdx.y;             // hb = h*BB + b
  int h = hb >> 1, b = hb & 1;
  int t = threadIdx.x;
  __shared__ float dl[DH];
  int i = topidx[hb * USEL + u];
  if (t < DH) {
    float ss = 0.f, dr = 0.f;
#pragma unroll
    for (int sl = 0; sl < NJ; sl++) {
      const float* sp = ssum_part + (((size_t)sl * NH * BB + hb) * USEL + u) * 4;
      ss += sp[0] + sp[1] + sp[2] + sp[3];
      dr += delta_part[(((size_t)sl * NH * BB + hb) * USEL + u) * DH + t];
    }
    dl[t] = dr / ss - vmean[b * DH + t];
  }
  __syncthreads();
  const float* Wh = W + (size_t)h * DH * DM;
  float* orow = out + ((size_t)b * LQ + i) * DM;
#pragma unroll
  for (int rep = 0; rep < 4; rep++) {
    int o = rep * 256 + t;
    float acc = 0.f;
#pragma unroll 16
    for (int d = 0; d < DH; d++) acc += dl[d] * Wh[(size_t)d * DM + o];
    atomicAdd(&orow[o], acc);                       // heads may share a row
  }
}

// ---------------- host ----------------
extern "C" void kernel_launch(void* const* d_in, const int* in_sizes, int n_in,
                              void* d_out, int out_size, void* d_ws, size_t ws_size,
                              hipStream_t stream) {
  const float* q  = (const float*)d_in[0];
  const float* k  = (const float*)d_in[1];
  const float* v  = (const float*)d_in[2];
  const float* W  = (const float*)d_in[3];
  const float* bp = (const float*)d_in[4];
  float* out = (float*)d_out;

  // workspace: every buffer fully overwritten before read — nothing needs zeroing
  char* w = (char*)d_ws;
  float*    S          = (float*)w;     w += (size_t)BB * LQ * LK * 4;                 // 8 MB
  unsigned* mask_g     = (unsigned*)w;  w += (size_t)NH * BB * (LK / 32) * 4;          // 4 KB
  float*    kmean      = (float*)w;     w += (size_t)NH * BB * DH * 4;                 // 8 KB
  float*    vmean      = (float*)w;     w += (size_t)BB * DH * 4;                      // 512 B
  float*    base_part  = (float*)w;     w += (size_t)NH * BB * DM * 4;                 // 128 KB
  float*    delta_part = (float*)w;     w += (size_t)NJ * NH * BB * USEL * DH * 4;     // 2.23 MB
  float*    ssum_part  = (float*)w;     w += (size_t)NJ * NH * BB * USEL * 4 * 4;      // 139 KB
  float*    M          = (float*)w;     w += (size_t)NH * BB * LQ * 4;                 // 128 KB
  int*      topidx     = (int*)w;       w += (size_t)NH * BB * USEL * 4;               // 4.25 KB
  if ((size_t)(w - (char*)d_ws) > ws_size) return;

  k_prep_scores<<<NSC + NH * BB + BB, 256, 0, stream>>>(q, k, v, S, mask_g, kmean, vmean);
  k_M_base     <<<NMB + NH * BB * (DM / 256), 256, 0, stream>>>(q, S, mask_g, kmean, vmean, W, M, base_part);
  k_topk_fill  <<<NTK + (BB * LQ * DM / 4) / 256, 256, 0, stream>>>(M, topidx, base_part, bp, out);
  k_pv         <<<dim3(NJ, NH * BB), 256, 0, stream>>>(S, v, topidx, delta_part, ssum_part);
  k_corr       <<<dim3(USEL, NH * BB), 256, 0, stream>>>(W, topidx, delta_part, ssum_part, vmean, out);
}